// Round 16
// baseline (837.189 us; speedup 1.0000x reference)
//
#include <hip/hip_runtime.h>

#define PI_F 3.14159265358979323846f

template<int v> struct ic_t { static constexpr int value = v; };

template<int N, int I = 0, typename F>
__device__ __forceinline__ void sfor(F&& f) {
  if constexpr (I < N) { f(ic_t<I>{}); sfor<N, I + 1>(static_cast<F&&>(f)); }
}

__host__ __device__ constexpr int fold_idx(int t) {
  t &= 63;
  return (t <= 16) ? t : (t <= 32) ? (32 - t) : (t <= 48) ? (t - 32) : (64 - t);
}
__host__ __device__ constexpr float fold_sgn(int t) {
  t &= 63;
  return (t <= 16) ? 1.f : (t <= 48) ? -1.f : 1.f;
}

// cos(k*pi/32), k=0..16, f32-rounded literals (compile-time only -> 0 VGPRs).
__device__ constexpr float CCV[17] = {
  1.0f, 0.9951847266721969f, 0.9807852804032304f, 0.9569403357322088f,
  0.9238795325112867f, 0.8819212643483550f, 0.8314696123025452f,
  0.7730104533627370f, 0.7071067811865476f, 0.6343932841636455f,
  0.5555702330196022f, 0.4713967368259976f, 0.3826834323650898f,
  0.2902846772544623f, 0.1950903220161283f, 0.0980171403295606f, 0.0f};

// cos/sin(2*pi*T/64); T must be compile-time -> folds to a literal constant.
#define TCOS(T) (fold_sgn(T) * CCV[fold_idx(T)])
#define TSIN(T) (fold_sgn(((T) + 48) & 63) * CCV[fold_idx(((T) + 48) & 63)])

// One radix-4 j-group of the 64-pt real row DFT (r1/r11/r14-verified math).
// j = 4G+m; inputs x[j], x[j+16], x[j+32], x[j+48] (j is the LOCAL j').
template<int G>
__device__ __forceinline__ void row_group(const float4& qa, const float4& qb,
                                          const float4& qc, const float4& qd,
                                          float* Xr, float* Xi)
{
  sfor<4>([&](auto MC) {
    constexpr int m = decltype(MC)::value;
    constexpr int j = 4 * G + m;
    const float xa = (m == 0) ? qa.x : (m == 1) ? qa.y : (m == 2) ? qa.z : qa.w;
    const float xb = (m == 0) ? qb.x : (m == 1) ? qb.y : (m == 2) ? qb.z : qb.w;
    const float xc = (m == 0) ? qc.x : (m == 1) ? qc.y : (m == 2) ? qc.z : qc.w;
    const float xd = (m == 0) ? qd.x : (m == 1) ? qd.y : (m == 2) ? qd.z : qd.w;
    const float s02 = xa + xc, d02 = xa - xc;
    const float s13 = xb + xd, d31 = xd - xb;
    const float g0 = s02 + s13, g2 = s02 - s13;
    Xr[0] += g0;                                   // k2=0 (imag identically 0)
    sfor<3>([&](auto EC) {                         // k2 = 2,4,6
      constexpr int k2 = 2 * (decltype(EC)::value + 1);
      constexpr int t = (k2 * j) & 63;
      const float g = (k2 == 4) ? g0 : g2;
      Xr[k2] = fmaf(g,  TCOS(t), Xr[k2]);
      Xi[k2] = fmaf(-g, TSIN(t), Xi[k2]);
    });
    sfor<4>([&](auto UC) {                         // k2 = 1,3,5,7
      constexpr int k2 = 2 * decltype(UC)::value + 1;
      constexpr int t = (k2 * j) & 63;
      const float gr = d02;
      const float gi = ((k2 & 3) == 1) ? d31 : -d31;
      Xr[k2] = fmaf(gr, TCOS(t), fmaf(gi,  TSIN(t), Xr[k2]));
      Xi[k2] = fmaf(gi, TCOS(t), fmaf(-gr, TSIN(t), Xi[k2]));
    });
  });
}

// ---------------------------------------------------------------------------
// Kernel 1 (r16: coalesced staging, REGISTER-SAFE by phase separation).
// r14 (same coalescing idea) spilled because W[16] stayed live across the
// staging loop (peak > 64). r16 removes that: per n0 the wave stores only its
// stage-2 result z (z4[4] = 8 persistent regs); the k0-fold runs in a final
// phase from a Z-buffer in LDS (aliases the dead staging slabs, barriered).
// Phase peak ~52-56 regs (4-deep float4 in-flight, fenced; Xr/Xi 16; z4 8).
// Wave wv owns n0 in {4wv..4wv+3}; per n0:
//   stage 32 rows (8 KB contiguous) with 8 coalesced float4 loads/lane;
//   row DFT (r14-verified hf-split + shfl combine); Yc[8][33] aliases slab;
//   z[k1,k2] = sum_n1 Yc*tw32 -> z4[n0l] regs.
// Tail: barrier; Zb[n0][lane] <- z4 (Zb aliases Xw_); barrier;
//   mode tid (k0=wv, lane): sum_n0 Zb*tw32 -> dst[tid] (coalesced).
// ---------------------------------------------------------------------------
__global__ __launch_bounds__(512, 4)
void k1_fwd_dft(const float* __restrict__ qg, const float* __restrict__ kg,
                float2* __restrict__ qsel, float2* __restrict__ ksel)
{
  __shared__ float Xw_[8 * 2176];   // 8 waves x [32][68] dwords (69.6 KB)
  __shared__ float2 tw32[32];       // (cos,sin)(2*pi*t/32)

  const int tid = threadIdx.x;
  const int lane = tid & 63;
  const int wv = tid >> 6;                   // 0..7
  const int bid = blockIdx.x;
  const int ch = bid & 1023;
  const float* __restrict__ src = (bid < 1024 ? qg : kg) + (size_t)ch * 65536;
  float2* __restrict__ dst = (bid < 1024 ? qsel : ksel) + ch * 512;

  if (lane < 32) {                           // per-wave redundant init
    float s, c;
    sincosf((float)lane * (2.f * PI_F / 32.f), &s, &c);
    tw32[lane] = make_float2(c, s);
  }

  float* __restrict__ Xw = Xw_ + wv * 2176;  // wave-private [32][68]
  float2* __restrict__ Yc = (float2*)Xw;     // [8][33] f2, aliases rows 0..8

  const int r  = lane & 31;                  // staged row (= n1)
  const int hf = lane >> 5;                  // j-half
  const int k1c = lane >> 3;                 // stage-2 roles
  const int k2q = lane & 7;

  float z4r[4], z4i[4];                      // persistent: 8 regs only

  sfor<4>([&](auto NL) {
    constexpr int n0l = decltype(NL)::value;
    const int n0 = (wv << 2) + n0l;

    // ---- stage 32 rows (8 KB contiguous), fully coalesced, 4-deep batches
    {
      const float4* __restrict__ gs = (const float4*)(src + ((size_t)n0 << 11));
      float4 L0 = gs[lane],       L1 = gs[64 + lane],
             L2 = gs[128 + lane], L3 = gs[192 + lane];
      __builtin_amdgcn_sched_barrier(0);
      sfor<4>([&](auto IC) { constexpr int i = decltype(IC)::value;
        const int f = (i << 6) + lane;
        const float4 v = (i == 0) ? L0 : (i == 1) ? L1 : (i == 2) ? L2 : L3;
        *(float4*)&Xw[(f >> 4) * 68 + ((f & 15) << 2)] = v;
      });
      __builtin_amdgcn_sched_barrier(0);
      float4 M0 = gs[256 + lane], M1 = gs[320 + lane],
             M2 = gs[384 + lane], M3 = gs[448 + lane];
      __builtin_amdgcn_sched_barrier(0);
      sfor<4>([&](auto IC) { constexpr int i = decltype(IC)::value;
        const int f = ((i + 4) << 6) + lane;
        const float4 v = (i == 0) ? M0 : (i == 1) ? M1 : (i == 2) ? M2 : M3;
        *(float4*)&Xw[(f >> 4) * 68 + ((f & 15) << 2)] = v;
      });
      asm volatile("s_waitcnt lgkmcnt(0)" ::: "memory");
      __builtin_amdgcn_sched_barrier(0);
    }

    // ---- row DFT: lane (r, hf): groups G0,G1 on data offset 8*hf
    float Xr[8], Xi[8];
    sfor<8>([&](auto K) { constexpr int k = decltype(K)::value;
      Xr[k] = 0.f; Xi[k] = 0.f; });
    {
      const float* __restrict__ xrow = &Xw[r * 68 + (hf << 3)];
      float4 qa = *(const float4*)&xrow[0];
      float4 qb = *(const float4*)&xrow[16];
      float4 qc = *(const float4*)&xrow[32];
      float4 qd = *(const float4*)&xrow[48];
      row_group<0>(qa, qb, qc, qd, Xr, Xi);
      __builtin_amdgcn_sched_barrier(0);
      qa = *(const float4*)&xrow[4];
      qb = *(const float4*)&xrow[20];
      qc = *(const float4*)&xrow[36];
      qd = *(const float4*)&xrow[52];
      row_group<1>(qa, qb, qc, qd, Xr, Xi);
    }
    // hf=1: apply rotation e^{-i pi k2/4} (theta = 2*pi*(8*k2)/64, literal)
    if (hf) {
      sfor<8>([&](auto KC) {
        constexpr int k2 = decltype(KC)::value;
        constexpr int t = (8 * k2) & 63;
        const float nr = Xr[k2] * TCOS(t) + Xi[k2] * TSIN(t);
        const float ni = Xi[k2] * TCOS(t) - Xr[k2] * TSIN(t);
        Xr[k2] = nr; Xi[k2] = ni;
      });
    }
    // combine halves: both end with the full row-DFT
    sfor<8>([&](auto KC) {
      constexpr int k2 = decltype(KC)::value;
      Xr[k2] += __shfl_xor(Xr[k2], 32);
      Xi[k2] += __shfl_xor(Xi[k2], 32);
    });
    // Yc[k2][n1=r] (aliases Xw rows 0..8 -- all Xw reads complete above)
    if (!hf) {
      sfor<8>([&](auto KC) {
        constexpr int k2 = decltype(KC)::value;
        Yc[k2 * 33 + r] = make_float2(Xr[k2], Xi[k2]);
      });
    }
    asm volatile("s_waitcnt lgkmcnt(0)" ::: "memory");
    __builtin_amdgcn_sched_barrier(0);

    // ---- stage 2: lane (k1c,k2q): z = sum_n1 Yc * tw32 (conj)
    {
      float zr = 0.f, zi = 0.f;
      #pragma unroll
      for (int n1 = 0; n1 < 32; ++n1) {
        const float2 y = Yc[k2q * 33 + n1];        // 8 addrs/wave, broadcast
        const float2 w = tw32[(k1c * n1) & 31];
        zr = fmaf(y.x, w.x, fmaf( y.y, w.y, zr));
        zi = fmaf(y.y, w.x, fmaf(-y.x, w.y, zi));
      }
      z4r[n0l] = zr; z4i[n0l] = zi;                // static index (sfor)
    }
  });

  // ---- tail: Zb[n0][lane] (aliases Xw_; slabs dead), then k0-fold
  __syncthreads();
  float2* __restrict__ Zb = (float2*)Xw_;          // [32][stride 65] f2
  sfor<4>([&](auto JC) {
    constexpr int j = decltype(JC)::value;
    Zb[((wv << 2) + j) * 65 + lane] = make_float2(z4r[j], z4i[j]);
  });
  __syncthreads();
  {
    float sr = 0.f, si = 0.f;
    #pragma unroll
    for (int n0 = 0; n0 < 32; ++n0) {
      const float2 v = Zb[n0 * 65 + lane];         // 2-way banks: free
      const float2 w = tw32[(wv * n0) & 31];       // wave-uniform broadcast
      sr = fmaf(v.x, w.x, fmaf( v.y, w.y, sr));
      si = fmaf(v.y, w.x, fmaf(-v.x, w.y, si));
    }
    dst[tid] = make_float2(sr * (1.f / 256.f), si * (1.f / 256.f));
  }
}

// ---------------------------------------------------------------------------
// Kernel 2 (r12 e-split structure, kept): lane = (eh<1, x<32); thread owns
// 8 e-channels; dot completed via shfl_xor(32); fast intrinsics.
// ---------------------------------------------------------------------------
__global__ __launch_bounds__(512, 4)
void k2_attn(const float2* __restrict__ qsel, const float2* __restrict__ ksel,
             float2* __restrict__ xqkv)
{
  __shared__ float2 Kl[8192];   // [e<16][y<512], reused as reduction buffer
  const int tid = threadIdx.x;
  const int bh = blockIdx.x >> 4;
  const int xo = blockIdx.x & 15;

  const float2* __restrict__ kb = ksel + bh * 8192;
  for (int i = tid; i < 8192; i += 512) Kl[i] = kb[i];

  const int lane = tid & 63;
  const int yg = tid >> 6;            // 0..7 (wave = y-group)
  const int xl = lane & 31;
  const int eh = lane >> 5;           // 0/1: e-half
  const int x = xo * 32 + xl;
  const int e0 = eh * 8;

  const float2* __restrict__ qb = qsel + bh * 8192;
  float qr[8], qi[8], ar[8], ai[8];
  sfor<8>([&](auto E) {
    constexpr int el = decltype(E)::value;
    const float2 v = qb[(e0 + el) * 512 + x];
    qr[el] = v.x; qi[el] = v.y;
    ar[el] = 0.f; ai[el] = 0.f;
  });
  __syncthreads();

  const int y0 = yg * 64;
  for (int y = y0; y < y0 + 64; ++y) {
    float kr[8], ki[8];
    float sr = 0.f, si = 0.f;
    sfor<8>([&](auto E) {
      constexpr int el = decltype(E)::value;
      const float2 v = Kl[(e0 + el) * 512 + y];   // 2-addr broadcast per wave
      kr[el] = v.x; ki[el] = v.y;
      sr = fmaf(qr[el], v.x, fmaf(-qi[el], v.y, sr));
      si = fmaf(qr[el], v.y, fmaf( qi[el], v.x, si));
    });
    // complete dot across e-halves (partner lane = lane ^ 32)
    sr += __shfl_xor(sr, 32);
    si += __shfl_xor(si, 32);
    // complex tanh(sr + i si) = (sinh 2a + i sin 2b) / (cosh 2a + cos 2b)
    float a2 = 2.f * sr;
    a2 = fminf(fmaxf(a2, -30.f), 30.f);
    const float b2 = 2.f * si;
    const float ea = __expf(a2);
    const float ei = 1.f / ea;
    const float sh = 0.5f * (ea - ei);
    const float chp = 0.5f * (ea + ei);
    float sb, cb;
    __sincosf(b2, &sb, &cb);
    const float inv = 1.f / (chp + cb);
    const float tr = sh * inv;
    const float ti = sb * inv;
    sfor<8>([&](auto E) {
      constexpr int el = decltype(E)::value;
      ar[el] = fmaf(tr, kr[el], fmaf(-ti, ki[el], ar[el]));
      ai[el] = fmaf(tr, ki[el], fmaf( ti, kr[el], ai[el]));
    });
  }
  __syncthreads();
  float* __restrict__ red = (float*)Kl;   // K dead; 16384 floats available
  if (yg) {
    const int g = yg - 1;                 // 0..6; group = 1024 floats
    sfor<8>([&](auto E) {
      constexpr int el = decltype(E)::value;
      red[g * 1024 + (eh * 8 + el) * 64 + 2 * xl]     = ar[el];
      red[g * 1024 + (eh * 8 + el) * 64 + 2 * xl + 1] = ai[el];
    });
  }
  __syncthreads();
  if (!yg) {
    float2* __restrict__ ob = xqkv + bh * 8192;
    sfor<8>([&](auto E) {
      constexpr int el = decltype(E)::value;
      float sr2 = ar[el], si2 = ai[el];
      #pragma unroll
      for (int g = 0; g < 7; ++g) {
        sr2 += red[g * 1024 + (eh * 8 + el) * 64 + 2 * xl];
        si2 += red[g * 1024 + (eh * 8 + el) * 64 + 2 * xl + 1];
      }
      ob[(e0 + el) * 512 + x] = make_float2(sr2, si2);
    });
  }
}

// ---------------------------------------------------------------------------
// Kernel 3 (r15): w-multiply + analytic canonicalized inverse transform.
// Stage-C twiddles are literal CCV (0 regs).
// ---------------------------------------------------------------------------
#define SCALE_OUT (1.f / 4194304.f)

__global__ __launch_bounds__(256, 2)
void k3_inv(const float2* __restrict__ xqkv, const float* __restrict__ w_re,
            const float* __restrict__ w_im, float* __restrict__ out)
{
  __shared__ float2 Fs[512];
  __shared__ float cn[64];                   // cos(2*pi*t/64)
  __shared__ float Ur[4096], Ui[4096];       // [p=k0*8+k1][n2]
  __shared__ float Vr[2048], Vi[2048];       // [k0*4+n1loc][n2], 4-n1 chunks

  const int tid = threadIdx.x;
  const int bho = blockIdx.x;
  const int o = bho & 15;
  const int h = (bho >> 4) & 7;
  const int bh = bho >> 4;                   // b*8+h

  if (tid < 64) cn[tid] = cosf((float)tid * (PI_F / 32.f));

  // F[x] = sum_e xqkv[e,x] * w[e,o,x], scaled
  const float2* __restrict__ xb = xqkv + bh * 8192;
  const float* __restrict__ wrb = w_re + ((size_t)(h * 256 + o)) * 512;
  const float* __restrict__ wib = w_im + ((size_t)(h * 256 + o)) * 512;
  for (int x = tid; x < 512; x += 256) {
    float fr = 0.f, fi = 0.f;
    sfor<16>([&](auto E) {
      constexpr int e = decltype(E)::value;
      const float2 v = xb[e * 512 + x];
      const float wr = wrb[e * 8192 + x];
      const float wi = wib[e * 8192 + x];
      fr = fmaf(v.x, wr, fmaf(-v.y, wi, fr));
      fi = fmaf(v.x, wi, fmaf( v.y, wr, fi));
    });
    Fs[x] = make_float2(fr * SCALE_OUT, fi * SCALE_OUT);
  }
  __syncthreads();

  const int n2 = tid & 63;
  const int wv = tid >> 6;

  // stage A: U[p][n2] = sum_k2 w2(k2) cos(2pi k2 n2/64) F[p*8+k2]
  #pragma unroll
  for (int i = 0; i < 16; ++i) {
    const int p = wv * 16 + i;
    float ur = 0.f, ui = 0.f;
    sfor<8>([&](auto KC) {
      constexpr int k2 = decltype(KC)::value;
      const float2 f = Fs[p * 8 + k2];       // wave-uniform broadcast
      const float cv = cn[(k2 * n2) & 63];
      const float wgt = (k2 == 0) ? cv : 2.f * cv;
      ur = fmaf(wgt, f.x, ur);
      ui = fmaf(wgt, f.y, ui);
    });
    Ur[p * 64 + n2] = ur;
    Ui[p * 64 + n2] = ui;
  }
  __syncthreads();

  // per-thread U registers for its two k0 columns
  float u_r[2][8], u_i[2][8];
  sfor<2>([&](auto JC) {
    constexpr int j = decltype(JC)::value;
    sfor<8>([&](auto KC) {
      constexpr int k1 = decltype(KC)::value;
      const int p = (wv * 2 + j) * 8 + k1;
      u_r[j][k1] = Ur[p * 64 + n2];
      u_i[j][k1] = Ui[p * 64 + n2];
    });
  });

  float* __restrict__ ob = out + (size_t)bho * 65536;

  for (int chq = 0; chq < 8; ++chq) {        // 4 n1 values per chunk
    // stage B: V[k0][n1loc][n2] = sum_k1 U * e^{+i 2pi k1 n1/32}
    sfor<2>([&](auto JC) {
      constexpr int j = decltype(JC)::value;
      const int k0 = wv * 2 + j;
      sfor<4>([&](auto LC) {
        constexpr int l = decltype(LC)::value;
        const int n1 = chq * 4 + l;
        float vr = 0.f, vi = 0.f;
        sfor<8>([&](auto KC) {
          constexpr int k1 = decltype(KC)::value;
          const int t = (2 * k1 * n1) & 63;  // wave-uniform -> broadcast reads
          const float cv = cn[t];
          const float sv = cn[(t + 48) & 63];
          vr = fmaf(u_r[j][k1], cv, fmaf(-u_i[j][k1], sv, vr));
          vi = fmaf(u_r[j][k1], sv, fmaf( u_i[j][k1], cv, vi));
        });
        Vr[(k0 * 4 + l) * 64 + n2] = vr;
        Vi[(k0 * 4 + l) * 64 + n2] = vi;
      });
    });
    __syncthreads();
    // stage C: out[n0][n1][n2] = sum_k0 Vr cos - Vi sin (literal twiddles)
    {
      const int l = wv;
      float vrr[8], vii[8];
      sfor<8>([&](auto KC) {
        constexpr int k0 = decltype(KC)::value;
        vrr[k0] = Vr[(k0 * 4 + l) * 64 + n2];
        vii[k0] = Vi[(k0 * 4 + l) * 64 + n2];
      });
      const int n1 = chq * 4 + l;
      float* __restrict__ op = ob + n1 * 64 + n2;
      sfor<32>([&](auto NC) {
        constexpr int n0 = decltype(NC)::value;
        float acc = vrr[0];
        sfor<7>([&](auto KC) {
          constexpr int k0 = decltype(KC)::value + 1;
          constexpr int t = (2 * k0 * n0) & 63;
          acc = fmaf(vrr[k0], TCOS(t), fmaf(-vii[k0], TSIN(t), acc));
        });
        op[n0 * 2048] = acc;
      });
    }
    __syncthreads();
  }
}

// ---------------------------------------------------------------------------
extern "C" void kernel_launch(void* const* d_in, const int* in_sizes, int n_in,
                              void* d_out, int out_size, void* d_ws, size_t ws_size,
                              hipStream_t stream)
{
  (void)in_sizes; (void)n_in; (void)out_size; (void)ws_size;
  const float* q    = (const float*)d_in[0];
  const float* k    = (const float*)d_in[1];
  const float* w_re = (const float*)d_in[2];
  const float* w_im = (const float*)d_in[3];
  float* out = (float*)d_out;

  // workspace: qsel(4MB) | ksel(4MB) | xqkv(4MB), all [bh][e][x] float2
  float2* qsel = (float2*)d_ws;
  float2* ksel = qsel + 1024 * 512;
  float2* xqkv = ksel + 1024 * 512;

  hipLaunchKernelGGL(k1_fwd_dft, dim3(2048), dim3(512), 0, stream, q, k, qsel, ksel);
  hipLaunchKernelGGL(k2_attn,    dim3(1024), dim3(512), 0, stream, qsel, ksel, xqkv);
  hipLaunchKernelGGL(k3_inv,     dim3(1024), dim3(256), 0, stream, xqkv, w_re, w_im, out);
}

// Round 17
// 297.276 us; speedup vs baseline: 2.8162x; 2.8162x over previous
//
#include <hip/hip_runtime.h>

#define PI_F 3.14159265358979323846f

template<int v> struct ic_t { static constexpr int value = v; };

template<int N, int I = 0, typename F>
__device__ __forceinline__ void sfor(F&& f) {
  if constexpr (I < N) { f(ic_t<I>{}); sfor<N, I + 1>(static_cast<F&&>(f)); }
}

__host__ __device__ constexpr int fold_idx(int t) {
  t &= 63;
  return (t <= 16) ? t : (t <= 32) ? (32 - t) : (t <= 48) ? (t - 32) : (64 - t);
}
__host__ __device__ constexpr float fold_sgn(int t) {
  t &= 63;
  return (t <= 16) ? 1.f : (t <= 48) ? -1.f : 1.f;
}

// cos(k*pi/32), k=0..16, f32-rounded literals (compile-time only -> 0 VGPRs).
__device__ constexpr float CCV[17] = {
  1.0f, 0.9951847266721969f, 0.9807852804032304f, 0.9569403357322088f,
  0.9238795325112867f, 0.8819212643483550f, 0.8314696123025452f,
  0.7730104533627370f, 0.7071067811865476f, 0.6343932841636455f,
  0.5555702330196022f, 0.4713967368259976f, 0.3826834323650898f,
  0.2902846772544623f, 0.1950903220161283f, 0.0980171403295606f, 0.0f};

// cos/sin(2*pi*T/64); T must be compile-time -> folds to a literal constant.
#define TCOS(T) (fold_sgn(T) * CCV[fold_idx(T)])
#define TSIN(T) (fold_sgn(((T) + 48) & 63) * CCV[fold_idx(((T) + 48) & 63)])

// One radix-4 j-group of the 64-pt real row DFT (r1/r11-verified math).
// j = 4G+m in 0..15; inputs x[j], x[j+16], x[j+32], x[j+48].
template<int G>
__device__ __forceinline__ void row_group(const float4& qa, const float4& qb,
                                          const float4& qc, const float4& qd,
                                          float* Xr, float* Xi)
{
  sfor<4>([&](auto MC) {
    constexpr int m = decltype(MC)::value;
    constexpr int j = 4 * G + m;
    const float xa = (m == 0) ? qa.x : (m == 1) ? qa.y : (m == 2) ? qa.z : qa.w;
    const float xb = (m == 0) ? qb.x : (m == 1) ? qb.y : (m == 2) ? qb.z : qb.w;
    const float xc = (m == 0) ? qc.x : (m == 1) ? qc.y : (m == 2) ? qc.z : qc.w;
    const float xd = (m == 0) ? qd.x : (m == 1) ? qd.y : (m == 2) ? qd.z : qd.w;
    const float s02 = xa + xc, d02 = xa - xc;
    const float s13 = xb + xd, d31 = xd - xb;
    const float g0 = s02 + s13, g2 = s02 - s13;
    Xr[0] += g0;                                   // k2=0 (imag identically 0)
    sfor<3>([&](auto EC) {                         // k2 = 2,4,6
      constexpr int k2 = 2 * (decltype(EC)::value + 1);
      constexpr int t = (k2 * j) & 63;
      const float g = (k2 == 4) ? g0 : g2;
      Xr[k2] = fmaf(g,  TCOS(t), Xr[k2]);
      Xi[k2] = fmaf(-g, TSIN(t), Xi[k2]);
    });
    sfor<4>([&](auto UC) {                         // k2 = 1,3,5,7
      constexpr int k2 = 2 * decltype(UC)::value + 1;
      constexpr int t = (k2 * j) & 63;
      const float gr = d02;
      const float gi = ((k2 & 3) == 1) ? d31 : -d31;
      Xr[k2] = fmaf(gr, TCOS(t), fmaf(gi,  TSIN(t), Xr[k2]));
      Xi[k2] = fmaf(gi, TCOS(t), fmaf(-gr, TSIN(t), Xi[k2]));
    });
  });
}

// ---------------------------------------------------------------------------
// Kernel 1 (r11 design, FINAL — the only verified no-spill k1: VGPR 64,
// WRITE 8 MB, ~165 us). r10/r14/r16 coalescing restructures all spilled
// (WRITE 0.6-4.8 GB); r13 wave-decoupling was neutral. Accepted local optimum.
// n2-first row DFT; stage 2+3 fused; 2-barrier reduction tail.
// ---------------------------------------------------------------------------
__global__ __launch_bounds__(512, 4)
void k1_fwd_dft(const float* __restrict__ qg, const float* __restrict__ kg,
                float2* __restrict__ qsel, float2* __restrict__ ksel)
{
  __shared__ float2 Yb[8 * 1036];   // [k2][row<=1023], 66.3 KB; partials alias
  __shared__ float2 tw32[32];       // (cos,sin)(2*pi*t/32)

  const int tid = threadIdx.x;
  const int lane = tid & 63;
  const int wv = tid >> 6;                   // 0..7
  const int bid = blockIdx.x;
  const int ch = bid & 1023;
  const float* __restrict__ src = (bid < 1024 ? qg : kg) + (size_t)ch * 65536;
  float2* __restrict__ dst = (bid < 1024 ? qsel : ksel) + ch * 512;

  if (tid < 32) {
    float s, c;
    sincosf((float)tid * (2.f * PI_F / 32.f), &s, &c);
    tw32[tid] = make_float2(c, s);
  }

  // ---- stage 1: rows 0..1023 in two passes; Y[k2][row] <- row DFT
  #pragma unroll
  for (int p = 0; p < 2; ++p) {
    const int row = (p << 9) + tid;
    const float4* __restrict__ rq = (const float4*)(src + ((size_t)row << 6));
    float Xr[8], Xi[8];
    sfor<8>([&](auto K) { constexpr int k = decltype(K)::value;
      Xr[k] = 0.f; Xi[k] = 0.f; });

    // A/B pipelined loads: groups g use rq[g], rq[g+4], rq[g+8], rq[g+12]
    float4 A0 = rq[0], A1 = rq[4], A2 = rq[8],  A3 = rq[12];
    float4 B0 = rq[1], B1 = rq[5], B2 = rq[9],  B3 = rq[13];
    __builtin_amdgcn_sched_barrier(0);
    row_group<0>(A0, A1, A2, A3, Xr, Xi);
    __builtin_amdgcn_sched_barrier(0);
    A0 = rq[2]; A1 = rq[6]; A2 = rq[10]; A3 = rq[14];
    __builtin_amdgcn_sched_barrier(0);
    row_group<1>(B0, B1, B2, B3, Xr, Xi);
    __builtin_amdgcn_sched_barrier(0);
    B0 = rq[3]; B1 = rq[7]; B2 = rq[11]; B3 = rq[15];
    __builtin_amdgcn_sched_barrier(0);
    row_group<2>(A0, A1, A2, A3, Xr, Xi);
    __builtin_amdgcn_sched_barrier(0);
    row_group<3>(B0, B1, B2, B3, Xr, Xi);

    sfor<8>([&](auto KC) {
      constexpr int k2 = decltype(KC)::value;
      Yb[k2 * 1036 + row] = make_float2(Xr[k2], Xi[k2]);  // consecutive lanes
    });
  }
  __syncthreads();

  // ---- stage 2+3 fused: n1-DFT then k0-fold into register partials
  const int k1 = lane >> 3;
  const int k2 = lane & 7;
  float Wr[8], Wi[8];
  sfor<8>([&](auto K) { constexpr int k = decltype(K)::value;
    Wr[k] = 0.f; Wi[k] = 0.f; });

  sfor<4>([&](auto QC) {
    constexpr int q = decltype(QC)::value;
    const int n0 = wv + 8 * q;                  // wave-uniform
    const float2* __restrict__ yp = &Yb[k2 * 1036 + n0 * 32];
    float zr = 0.f, zi = 0.f;
    #pragma unroll
    for (int n1 = 0; n1 < 32; ++n1) {
      const float2 y = yp[n1];                  // 8-addr broadcast groups
      const float2 w = tw32[(k1 * n1) & 31];
      zr = fmaf(y.x, w.x, fmaf( y.y, w.y, zr));
      zi = fmaf(y.y, w.x, fmaf(-y.x, w.y, zi));
    }
    sfor<8>([&](auto KC) {
      constexpr int k0 = decltype(KC)::value;
      const float2 w = tw32[(k0 * n0) & 31];    // wave-uniform broadcast
      Wr[k0] = fmaf(zr, w.x, fmaf( zi, w.y, Wr[k0]));
      Wi[k0] = fmaf(zi, w.x, fmaf(-zr, w.y, Wi[k0]));
    });
  });
  __syncthreads();                              // all Y reads done

  // partials part[k0][wv][lane] into (dead) Y region: 32 KB
  float2* __restrict__ part = Yb;
  sfor<8>([&](auto KC) {
    constexpr int k0 = decltype(KC)::value;
    part[k0 * 512 + (wv << 6) + lane] = make_float2(Wr[k0], Wi[k0]);
  });
  __syncthreads();

  // reduce 8 wave-partials; thread tid owns mode (k0=wv, k1, k2) = tid
  {
    const float2* __restrict__ pp = &part[(wv << 9) + lane];
    float sr = 0.f, si = 0.f;
    #pragma unroll
    for (int w8 = 0; w8 < 8; ++w8) {
      const float2 v = pp[w8 * 64];
      sr += v.x; si += v.y;
    }
    dst[tid] = make_float2(sr * (1.f / 256.f), si * (1.f / 256.f));
  }
}

// ---------------------------------------------------------------------------
// Kernel 2 (r12 e-split + r17 rcp): lane = (eh<1, x<32); thread owns 8
// e-channels; dot completed via shfl_xor(32); fast __expf/__sincosf.
// r17: both float divides on the tanh critical path replaced with
// v_rcp_f32 (__builtin_amdgcn_rcpf): ~1e-6 rel error, output contribution
// ~6e-13 vs 1.17e-8 budget; saves ~20 serial inst per y-iteration.
// ---------------------------------------------------------------------------
__global__ __launch_bounds__(512, 4)
void k2_attn(const float2* __restrict__ qsel, const float2* __restrict__ ksel,
             float2* __restrict__ xqkv)
{
  __shared__ float2 Kl[8192];   // [e<16][y<512], reused as reduction buffer
  const int tid = threadIdx.x;
  const int bh = blockIdx.x >> 4;
  const int xo = blockIdx.x & 15;

  const float2* __restrict__ kb = ksel + bh * 8192;
  for (int i = tid; i < 8192; i += 512) Kl[i] = kb[i];

  const int lane = tid & 63;
  const int yg = tid >> 6;            // 0..7 (wave = y-group)
  const int xl = lane & 31;
  const int eh = lane >> 5;           // 0/1: e-half
  const int x = xo * 32 + xl;
  const int e0 = eh * 8;

  const float2* __restrict__ qb = qsel + bh * 8192;
  float qr[8], qi[8], ar[8], ai[8];
  sfor<8>([&](auto E) {
    constexpr int el = decltype(E)::value;
    const float2 v = qb[(e0 + el) * 512 + x];
    qr[el] = v.x; qi[el] = v.y;
    ar[el] = 0.f; ai[el] = 0.f;
  });
  __syncthreads();

  const int y0 = yg * 64;
  for (int y = y0; y < y0 + 64; ++y) {
    float kr[8], ki[8];
    float sr = 0.f, si = 0.f;
    sfor<8>([&](auto E) {
      constexpr int el = decltype(E)::value;
      const float2 v = Kl[(e0 + el) * 512 + y];   // 2-addr broadcast per wave
      kr[el] = v.x; ki[el] = v.y;
      sr = fmaf(qr[el], v.x, fmaf(-qi[el], v.y, sr));
      si = fmaf(qr[el], v.y, fmaf( qi[el], v.x, si));
    });
    // complete dot across e-halves (partner lane = lane ^ 32)
    sr += __shfl_xor(sr, 32);
    si += __shfl_xor(si, 32);
    // complex tanh(sr + i si) = (sinh 2a + i sin 2b) / (cosh 2a + cos 2b)
    float a2 = 2.f * sr;
    a2 = fminf(fmaxf(a2, -30.f), 30.f);
    const float b2 = 2.f * si;
    const float ea = __expf(a2);
    const float ei = __builtin_amdgcn_rcpf(ea);        // v_rcp_f32
    const float sh = 0.5f * (ea - ei);
    const float chp = 0.5f * (ea + ei);
    float sb, cb;
    __sincosf(b2, &sb, &cb);
    const float inv = __builtin_amdgcn_rcpf(chp + cb); // v_rcp_f32
    const float tr = sh * inv;
    const float ti = sb * inv;
    sfor<8>([&](auto E) {
      constexpr int el = decltype(E)::value;
      ar[el] = fmaf(tr, kr[el], fmaf(-ti, ki[el], ar[el]));
      ai[el] = fmaf(tr, ki[el], fmaf( ti, kr[el], ai[el]));
    });
  }
  __syncthreads();
  float* __restrict__ red = (float*)Kl;   // K dead; 16384 floats available
  if (yg) {
    const int g = yg - 1;                 // 0..6; group = 1024 floats
    sfor<8>([&](auto E) {
      constexpr int el = decltype(E)::value;
      red[g * 1024 + (eh * 8 + el) * 64 + 2 * xl]     = ar[el];
      red[g * 1024 + (eh * 8 + el) * 64 + 2 * xl + 1] = ai[el];
    });
  }
  __syncthreads();
  if (!yg) {
    float2* __restrict__ ob = xqkv + bh * 8192;
    sfor<8>([&](auto E) {
      constexpr int el = decltype(E)::value;
      float sr2 = ar[el], si2 = ai[el];
      #pragma unroll
      for (int g = 0; g < 7; ++g) {
        sr2 += red[g * 1024 + (eh * 8 + el) * 64 + 2 * xl];
        si2 += red[g * 1024 + (eh * 8 + el) * 64 + 2 * xl + 1];
      }
      ob[(e0 + el) * 512 + x] = make_float2(sr2, si2);
    });
  }
}

// ---------------------------------------------------------------------------
// Kernel 3 (r15): w-multiply + analytic canonicalized inverse transform.
// Stage-C twiddles are literal CCV (0 regs).
// ---------------------------------------------------------------------------
#define SCALE_OUT (1.f / 4194304.f)

__global__ __launch_bounds__(256, 2)
void k3_inv(const float2* __restrict__ xqkv, const float* __restrict__ w_re,
            const float* __restrict__ w_im, float* __restrict__ out)
{
  __shared__ float2 Fs[512];
  __shared__ float cn[64];                   // cos(2*pi*t/64)
  __shared__ float Ur[4096], Ui[4096];       // [p=k0*8+k1][n2]
  __shared__ float Vr[2048], Vi[2048];       // [k0*4+n1loc][n2], 4-n1 chunks

  const int tid = threadIdx.x;
  const int bho = blockIdx.x;
  const int o = bho & 15;
  const int h = (bho >> 4) & 7;
  const int bh = bho >> 4;                   // b*8+h

  if (tid < 64) cn[tid] = cosf((float)tid * (PI_F / 32.f));

  // F[x] = sum_e xqkv[e,x] * w[e,o,x], scaled
  const float2* __restrict__ xb = xqkv + bh * 8192;
  const float* __restrict__ wrb = w_re + ((size_t)(h * 256 + o)) * 512;
  const float* __restrict__ wib = w_im + ((size_t)(h * 256 + o)) * 512;
  for (int x = tid; x < 512; x += 256) {
    float fr = 0.f, fi = 0.f;
    sfor<16>([&](auto E) {
      constexpr int e = decltype(E)::value;
      const float2 v = xb[e * 512 + x];
      const float wr = wrb[e * 8192 + x];
      const float wi = wib[e * 8192 + x];
      fr = fmaf(v.x, wr, fmaf(-v.y, wi, fr));
      fi = fmaf(v.x, wi, fmaf( v.y, wr, fi));
    });
    Fs[x] = make_float2(fr * SCALE_OUT, fi * SCALE_OUT);
  }
  __syncthreads();

  const int n2 = tid & 63;
  const int wv = tid >> 6;

  // stage A: U[p][n2] = sum_k2 w2(k2) cos(2pi k2 n2/64) F[p*8+k2]
  #pragma unroll
  for (int i = 0; i < 16; ++i) {
    const int p = wv * 16 + i;
    float ur = 0.f, ui = 0.f;
    sfor<8>([&](auto KC) {
      constexpr int k2 = decltype(KC)::value;
      const float2 f = Fs[p * 8 + k2];       // wave-uniform broadcast
      const float cv = cn[(k2 * n2) & 63];
      const float wgt = (k2 == 0) ? cv : 2.f * cv;
      ur = fmaf(wgt, f.x, ur);
      ui = fmaf(wgt, f.y, ui);
    });
    Ur[p * 64 + n2] = ur;
    Ui[p * 64 + n2] = ui;
  }
  __syncthreads();

  // per-thread U registers for its two k0 columns
  float u_r[2][8], u_i[2][8];
  sfor<2>([&](auto JC) {
    constexpr int j = decltype(JC)::value;
    sfor<8>([&](auto KC) {
      constexpr int k1 = decltype(KC)::value;
      const int p = (wv * 2 + j) * 8 + k1;
      u_r[j][k1] = Ur[p * 64 + n2];
      u_i[j][k1] = Ui[p * 64 + n2];
    });
  });

  float* __restrict__ ob = out + (size_t)bho * 65536;

  for (int chq = 0; chq < 8; ++chq) {        // 4 n1 values per chunk
    // stage B: V[k0][n1loc][n2] = sum_k1 U * e^{+i 2pi k1 n1/32}
    sfor<2>([&](auto JC) {
      constexpr int j = decltype(JC)::value;
      const int k0 = wv * 2 + j;
      sfor<4>([&](auto LC) {
        constexpr int l = decltype(LC)::value;
        const int n1 = chq * 4 + l;
        float vr = 0.f, vi = 0.f;
        sfor<8>([&](auto KC) {
          constexpr int k1 = decltype(KC)::value;
          const int t = (2 * k1 * n1) & 63;  // wave-uniform -> broadcast reads
          const float cv = cn[t];
          const float sv = cn[(t + 48) & 63];
          vr = fmaf(u_r[j][k1], cv, fmaf(-u_i[j][k1], sv, vr));
          vi = fmaf(u_r[j][k1], sv, fmaf( u_i[j][k1], cv, vi));
        });
        Vr[(k0 * 4 + l) * 64 + n2] = vr;
        Vi[(k0 * 4 + l) * 64 + n2] = vi;
      });
    });
    __syncthreads();
    // stage C: out[n0][n1][n2] = sum_k0 Vr cos - Vi sin (literal twiddles)
    {
      const int l = wv;
      float vrr[8], vii[8];
      sfor<8>([&](auto KC) {
        constexpr int k0 = decltype(KC)::value;
        vrr[k0] = Vr[(k0 * 4 + l) * 64 + n2];
        vii[k0] = Vi[(k0 * 4 + l) * 64 + n2];
      });
      const int n1 = chq * 4 + l;
      float* __restrict__ op = ob + n1 * 64 + n2;
      sfor<32>([&](auto NC) {
        constexpr int n0 = decltype(NC)::value;
        float acc = vrr[0];
        sfor<7>([&](auto KC) {
          constexpr int k0 = decltype(KC)::value + 1;
          constexpr int t = (2 * k0 * n0) & 63;
          acc = fmaf(vrr[k0], TCOS(t), fmaf(-vii[k0], TSIN(t), acc));
        });
        op[n0 * 2048] = acc;
      });
    }
    __syncthreads();
  }
}

// ---------------------------------------------------------------------------
extern "C" void kernel_launch(void* const* d_in, const int* in_sizes, int n_in,
                              void* d_out, int out_size, void* d_ws, size_t ws_size,
                              hipStream_t stream)
{
  (void)in_sizes; (void)n_in; (void)out_size; (void)ws_size;
  const float* q    = (const float*)d_in[0];
  const float* k    = (const float*)d_in[1];
  const float* w_re = (const float*)d_in[2];
  const float* w_im = (const float*)d_in[3];
  float* out = (float*)d_out;

  // workspace: qsel(4MB) | ksel(4MB) | xqkv(4MB), all [bh][e][x] float2
  float2* qsel = (float2*)d_ws;
  float2* ksel = qsel + 1024 * 512;
  float2* xqkv = ksel + 1024 * 512;

  hipLaunchKernelGGL(k1_fwd_dft, dim3(2048), dim3(512), 0, stream, q, k, qsel, ksel);
  hipLaunchKernelGGL(k2_attn,    dim3(1024), dim3(512), 0, stream, qsel, ksel, xqkv);
  hipLaunchKernelGGL(k3_inv,     dim3(1024), dim3(256), 0, stream, xqkv, w_re, w_im, out);
}